// Round 6
// baseline (4746.409 us; speedup 1.0000x reference)
//
#include <hip/hip_runtime.h>
#include <hip/hip_bf16.h>

typedef __hip_bfloat16 bf16;

__device__ __forceinline__ float tof(bf16 v) { return __bfloat162float(v); }
__device__ __forceinline__ float ldf(const float* p) { return *p; }
__device__ __forceinline__ float ldf(const bf16* p) { return __bfloat162float(*p); }
__device__ __forceinline__ void stf(float* p, float v) { *p = v; }
__device__ __forceinline__ void stf(bf16* p, float v) { *p = __float2bfloat16(v); }

// x is (2, 8, 56, 56, 384) fp32; WS=(2,7,7), SS=(1,3,3), 12 heads x 32. Output fp32.
constexpr int TOK   = 50176;      // 2*8*56*56
constexpr int CCH   = 384;
constexpr int NELEM = TOK * CCH;  // 19267584

// window-token index m (= b_*98 + n) -> token row in original (b,d,h,w) order.
// Bijection; LN1 gather source (shift+partition) and proj scatter dest (reverse+roll).
__device__ __forceinline__ int remap_row(int m) {
    int b_ = m / 98, n = m % 98;
    int b = b_ >> 8, wrem = b_ & 255;
    int dw = wrem >> 6, hw = (wrem >> 3) & 7, wwi = wrem & 7;
    int zd = n / 49, r = n % 49, zh = r / 7, zw = r % 7;
    int d = ((dw * 2 + zd) + 1) & 7;
    int h = hw * 7 + zh + 3; if (h >= 56) h -= 56;
    int w = wwi * 7 + zw + 3; if (w >= 56) w -= 56;
    return ((b * 8 + d) * 56 + h) * 56 + w;
}

// ---------------- LayerNorm (one wave per token), out bf16.
// SRC_INPUT: src = fp32 model input, rows gathered via remap; else src = internal bf16, identity.
template <bool SRC_INPUT>
__global__ __launch_bounds__(256) void ln_kernel(const void* __restrict__ srcv,
                                                 const float* __restrict__ g,
                                                 const float* __restrict__ be,
                                                 bf16* __restrict__ dst) {
    int wave = threadIdx.x >> 6, lane = threadIdx.x & 63;
    int t = blockIdx.x * 4 + wave;  // grid*4 == TOK
    int srcRow = SRC_INPUT ? remap_row(t) : t;
    float v[6];
    float s = 0.f, ss = 0.f;
#pragma unroll
    for (int j = 0; j < 6; ++j) {
        size_t idx = (size_t)srcRow * CCH + lane + 64 * j;
        v[j] = SRC_INPUT ? ((const float*)srcv)[idx] : tof(((const bf16*)srcv)[idx]);
        s += v[j];
        ss += v[j] * v[j];
    }
#pragma unroll
    for (int off = 32; off; off >>= 1) {
        s  += __shfl_xor(s, off, 64);
        ss += __shfl_xor(ss, off, 64);
    }
    float mean = s * (1.f / 384.f);
    float var  = ss * (1.f / 384.f) - mean * mean;
    float rstd = rsqrtf(var + 1e-5f);
    bf16* q = dst + (size_t)t * CCH;
#pragma unroll
    for (int j = 0; j < 6; ++j) {
        int c = lane + 64 * j;
        stf(q + c, (v[j] - mean) * rstd * g[c] + be[c]);
    }
}

// ---------------- Tiled GEMM: acc[m,n] = sum_k A[m,k] * Bw[n,k]; fp32 accum.
// A internal bf16; Bw/bias fp32 model weights (row = out feature).
// MODE 0: C = acc + bias                            (qkv; C bf16)
// MODE 1: C[remap(m)] = Xres[remap(m)] + acc + bias (proj+reverse+roll+residual; Xres fp32 x, C bf16)
// MODE 2: C = gelu(acc + bias)                       (fc1; C bf16 hid)
// MODE 4: C[m] = Xres[m] + acc + bias                (fc2+residual2; Xres bf16 x1, C fp32 = final out)
template <int MODE, typename CT, typename XT>
__global__ __launch_bounds__(256) void gemm_bt(const bf16* __restrict__ A, int lda,
                                               const float* __restrict__ Bw, int ldb,
                                               const float* __restrict__ bias,
                                               CT* __restrict__ Cc, int ldc,
                                               const XT* __restrict__ Xres,
                                               int M, int K) {
    __shared__ float As[16][64];
    __shared__ float Bs[16][64];
    const int tx = threadIdx.x, ty = threadIdx.y;
    const int tid = ty * 16 + tx;
    const int bm = blockIdx.y * 64, bn = blockIdx.x * 64;
    float acc[4][4] = {};

    for (int k0 = 0; k0 < K; k0 += 16) {
        for (int i = tid; i < 1024; i += 256) {
            int mm = i >> 4, kk = i & 15;
            int mrow = bm + mm; if (mrow >= M) mrow = M - 1;  // clamp (dup rows ok)
            As[kk][mm] = tof(A[(size_t)mrow * lda + k0 + kk]);
            Bs[kk][mm] = Bw[(size_t)(bn + mm) * ldb + k0 + kk];
        }
        __syncthreads();
#pragma unroll
        for (int kk = 0; kk < 16; ++kk) {
            float4 av = *(const float4*)&As[kk][ty * 4];
            float4 bv = *(const float4*)&Bs[kk][tx * 4];
            float a[4] = {av.x, av.y, av.z, av.w};
            float b[4] = {bv.x, bv.y, bv.z, bv.w};
#pragma unroll
            for (int im = 0; im < 4; ++im)
#pragma unroll
                for (int in = 0; in < 4; ++in) acc[im][in] += a[im] * b[in];
        }
        __syncthreads();
    }

#pragma unroll
    for (int im = 0; im < 4; ++im) {
        int m = bm + ty * 4 + im;
        if (m >= M) continue;
        int colb = bn + tx * 4;
        if (MODE == 1) {
            int dstr = remap_row(m);
#pragma unroll
            for (int in = 0; in < 4; ++in) {
                int c = colb + in;
                size_t xi = (size_t)dstr * ldc + c;
                stf(Cc + xi, ldf(Xres + xi) + acc[im][in] + bias[c]);
            }
        } else if (MODE == 0) {
#pragma unroll
            for (int in = 0; in < 4; ++in)
                stf(Cc + (size_t)m * ldc + colb + in, acc[im][in] + bias[colb + in]);
        } else if (MODE == 2) {
#pragma unroll
            for (int in = 0; in < 4; ++in) {
                float xv = acc[im][in] + bias[colb + in];
                stf(Cc + (size_t)m * ldc + colb + in,
                    0.5f * xv * (1.f + erff(xv * 0.70710678118654752f)));
            }
        } else {  // MODE 4
#pragma unroll
            for (int in = 0; in < 4; ++in) {
                int c = colb + in;
                size_t xi = (size_t)m * ldc + c;
                stf(Cc + xi, ldf(Xres + xi) + acc[im][in] + bias[c]);
            }
        }
    }
}

// ---------------- Attention: one block per (window-in-group, head). qkv internal bf16 rows
// [q(384)|k(384)|v(384)]; rpb fp32 input. gbase = first absolute window of this group.
__global__ __launch_bounds__(256) void attn_kernel(const bf16* __restrict__ qkv,
                                                   const float* __restrict__ rpb,
                                                   bf16* __restrict__ outw, int gbase) {
    __shared__ float qs[98 * 33];  // stride 33: no bank conflicts
    __shared__ float ks[98 * 33];
    __shared__ float sc[98 * 99];
    int bid = blockIdx.x;
    int head = bid % 12;
    int brel = bid / 12;
    int babs = gbase + brel;
    int tid = threadIdx.x;
    size_t rowbase = (size_t)brel * 98 * 1152 + head * 32;

    for (int i = tid; i < 98 * 32; i += 256) {
        int n = i >> 5, e = i & 31;
        qs[n * 33 + e] = tof(qkv[rowbase + (size_t)n * 1152 + e]) * 0.17677669529663687f;
        ks[n * 33 + e] = tof(qkv[rowbase + (size_t)n * 1152 + 384 + e]);
    }
    int wrem = babs & 255;
    int dw = wrem >> 6, hw = (wrem >> 3) & 7, wwi = wrem & 7;
    __syncthreads();

    for (int fl = tid; fl < 98 * 98; fl += 256) {
        int i = fl / 98, j = fl % 98;
        float s = 0.f;
#pragma unroll
        for (int kk = 0; kk < 32; ++kk) s += qs[i * 33 + kk] * ks[j * 33 + kk];
        int di = i / 49, ri = i % 49, hi = ri / 7, wi = ri % 7;
        int dj = j / 49, rj = j % 49, hj = rj / 7, wj = rj % 7;
        int idx = (di - dj + 1) * 169 + (hi - hj + 6) * 13 + (wi - wj + 6);
        s += rpb[(size_t)idx * 12 + head];
        int dpi = dw * 2 + di, hpi = hw * 7 + hi, wpi = wwi * 7 + wi;
        int dpj = dw * 2 + dj, hpj = hw * 7 + hj, wpj = wwi * 7 + wj;
        int ci = (dpi < 6 ? 0 : (dpi == 6 ? 1 : 2)) * 9 + (hpi < 49 ? 0 : (hpi < 53 ? 1 : 2)) * 3 +
                 (wpi < 49 ? 0 : (wpi < 53 ? 1 : 2));
        int cj = (dpj < 6 ? 0 : (dpj == 6 ? 1 : 2)) * 9 + (hpj < 49 ? 0 : (hpj < 53 ? 1 : 2)) * 3 +
                 (wpj < 49 ? 0 : (wpj < 53 ? 1 : 2));
        if (ci != cj) s -= 100.f;
        sc[i * 99 + j] = s;
    }
    __syncthreads();

    int wave = tid >> 6, lane = tid & 63;
    for (int r = wave; r < 98; r += 4) {
        float a0 = sc[r * 99 + lane];
        float a1 = (lane < 34) ? sc[r * 99 + 64 + lane] : -1e30f;
        float mx = fmaxf(a0, a1);
#pragma unroll
        for (int off = 32; off; off >>= 1) mx = fmaxf(mx, __shfl_xor(mx, off, 64));
        float e0 = __expf(a0 - mx);
        float e1 = (lane < 34) ? __expf(a1 - mx) : 0.f;
        float sm = e0 + e1;
#pragma unroll
        for (int off = 32; off; off >>= 1) sm += __shfl_xor(sm, off, 64);
        float inv = 1.f / sm;
        sc[r * 99 + lane] = e0 * inv;
        if (lane < 34) sc[r * 99 + 64 + lane] = e1 * inv;
    }
    __syncthreads();

    const bf16* vbase = qkv + rowbase + 768;
    for (int fl = tid; fl < 98 * 32; fl += 256) {
        int i = fl >> 5, e = fl & 31;
        float o = 0.f;
        for (int j = 0; j < 98; ++j) o += sc[i * 99 + j] * tof(vbase[(size_t)j * 1152 + e]);
        stf(outw + ((size_t)babs * 98 + i) * 384 + head * 32 + e, o);
    }
}

extern "C" void kernel_launch(void* const* d_in, const int* in_sizes, int n_in,
                              void* d_out, int out_size, void* d_ws, size_t ws_size,
                              hipStream_t stream) {
    const float* x      = (const float*)d_in[0];
    const float* n1w    = (const float*)d_in[1];
    const float* n1b    = (const float*)d_in[2];
    const float* qkv_w  = (const float*)d_in[3];
    const float* qkv_b  = (const float*)d_in[4];
    const float* rpb    = (const float*)d_in[5];
    const float* proj_w = (const float*)d_in[6];
    const float* proj_b = (const float*)d_in[7];
    const float* n2w    = (const float*)d_in[8];
    const float* n2b    = (const float*)d_in[9];
    const float* fc1_w  = (const float*)d_in[10];
    const float* fc1_b  = (const float*)d_in[11];
    const float* fc2_w  = (const float*)d_in[12];
    const float* fc2_b  = (const float*)d_in[13];

    // d_out (NELEM fp32 = 77 MB) doubles as staging:
    //   bytes [0, NELEM*2):        attn_out (bf16)   — dead after proj
    //   bytes [NELEM*2, NELEM*4):  xn2 (bf16)        — consumed per-group by fc1 before
    //                              fc2's fp32 final write frontier reaches it (verified)
    bf16*  aout = (bf16*)d_out;
    bf16*  xn2  = (bf16*)((char*)d_out + (size_t)NELEM * 2);
    float* fout = (float*)d_out;

    // d_ws: rA = NELEM bf16 (xw -> x1), rC = adaptive chunk scratch.
    bf16* rA = (bf16*)d_ws;
    bf16* rC = rA + (size_t)NELEM;
    size_t rCbytes = (ws_size > (size_t)NELEM * 2) ? ws_size - (size_t)NELEM * 2 : 0;

    // qkv group: W windows (512/W groups), needs W*98*1152*2 bytes in rC
    int W = 512;
    while (W > 1 && (size_t)W * 98 * 1152 * 2 > rCbytes) W >>= 1;
    int nqg = 512 / W;
    // MLP token group: Mt tokens, needs Mt*1536*2 bytes in rC
    int ngm = 1;
    while (ngm < 1024 && (size_t)(TOK / ngm) * 1536 * 2 > rCbytes) ngm <<= 1;
    int Mt = TOK / ngm;

    dim3 blk(256), blkg(16, 16);

    // 1. LN1 + shift + window partition: x -> rA (window-token order, bf16)
    ln_kernel<true><<<dim3(TOK / 4), blk, 0, stream>>>(x, n1w, n1b, rA);
    // 2. per group: QKV GEMM -> rC (bf16), attention -> aout (bf16)
    for (int g = 0; g < nqg; ++g) {
        int Mg = W * 98;
        gemm_bt<0, bf16, float><<<dim3(1152 / 64, (Mg + 63) / 64), blkg, 0, stream>>>(
            rA + (size_t)g * Mg * 384, 384, qkv_w, 384, qkv_b,
            rC, 1152, (const float*)nullptr, Mg, 384);
        attn_kernel<<<dim3(W * 12), blk, 0, stream>>>(rC, rpb, aout, g * W);
    }
    // 3. proj + window-reverse + roll + residual(x): aout -> rA (x1, bf16)
    gemm_bt<1, bf16, float><<<dim3(384 / 64, TOK / 64), blkg, 0, stream>>>(
        aout, 384, proj_w, 384, proj_b, rA, 384, x, TOK, 384);
    // 4. LN2(x1=rA) -> xn2 (bf16, upper half of d_out)
    ln_kernel<false><<<dim3(TOK / 4), blk, 0, stream>>>(rA, n2w, n2b, xn2);
    // 5. MLP per token group: fc1+gelu -> rC (bf16 hid), fc2 + x1 residual -> fout (fp32 final)
    for (int g = 0; g < ngm; ++g) {
        size_t off = (size_t)g * Mt * 384;
        gemm_bt<2, bf16, float><<<dim3(1536 / 64, (Mt + 63) / 64), blkg, 0, stream>>>(
            xn2 + off, 384, fc1_w, 384, fc1_b, rC, 1536, (const float*)nullptr, Mt, 384);
        gemm_bt<4, float, bf16><<<dim3(384 / 64, (Mt + 63) / 64), blkg, 0, stream>>>(
            rC, 1536, fc2_w, 1536, fc2_b, fout + off, 384, rA + off, Mt, 1536);
    }
}